// Round 7
// baseline (382.932 us; speedup 1.0000x reference)
//
#include <hip/hip_runtime.h>
#include <hip/hip_bf16.h>

#define N_NODES 50000
#define N_EDGES 1600000
#define HEADS 8
#define NBK 196   // buckets: dst>>8
#define NBLK 196  // edge tiles: 196*8192 >= 1.6M
#define EPB 8192  // edges per bucket-build block

typedef unsigned short u16;
typedef unsigned char u8;
typedef unsigned int u32;
typedef __attribute__((ext_vector_type(8))) short bf16x8;
typedef __attribute__((ext_vector_type(4))) float f32x4;

__device__ __forceinline__ float bf2f(u16 u) {
  union { u32 i; float f; } v; v.i = ((u32)u) << 16; return v.f;
}
__device__ __forceinline__ float bflo(u32 p) {
  union { u32 i; float f; } v; v.i = p << 16; return v.f;
}
__device__ __forceinline__ float bfhi(u32 p) {
  union { u32 i; float f; } v; v.i = p & 0xffff0000u; return v.f;
}
__device__ __forceinline__ u16 f2bf(float f) {
  union { float f; u32 i; } v; v.f = f;
  u32 r = v.i + 0x7fff + ((v.i >> 16) & 1);  // RNE
  return (u16)(r >> 16);
}
__device__ __forceinline__ u32 pack2(float a, float b) {
  return (u32)f2bf(a) | ((u32)f2bf(b) << 16);
}

// ---------------- dtype auto-detection ----------------
__global__ void k_detect(const u16* __restrict__ x, const u32* __restrict__ ei,
                         int* __restrict__ flags) {
  __shared__ int cbig, cnz;
  if (threadIdx.x == 0) { cbig = 0; cnz = 0; }
  __syncthreads();
  int lb = 0, ln = 0;
  for (int i = threadIdx.x; i < 4096; i += 256) {
    int ex = (x[i] >> 7) & 0xff;
    lb += (ex >= 140);
    if (i < 2048) ln += (ei[2 * i + 1] != 0);
  }
  atomicAdd(&cbig, lb); atomicAdd(&cnz, ln);
  __syncthreads();
  if (threadIdx.x == 0) {
    flags[0] = (cbig > 16) ? 1 : 0;   // 1: floats are fp32
    flags[1] = (cnz == 0) ? 1 : 0;    // 1: edge_index is int64
  }
}

// ---------------- converter: vectors -> fp32, W1/W2 -> transposed bf16 -------
__global__ void k_convsmall(const void* a1s, const void* a1d, const void* b1,
                            const void* gam, const void* bet, const void* a2s,
                            const void* a2d, const void* b2, const void* W1,
                            const void* W2, float* __restrict__ smallf,
                            u16* __restrict__ w1t, u16* __restrict__ w2t,
                            const int* __restrict__ flags) {
  int i = blockIdx.x * 256 + threadIdx.x;
  if (i >= 25408) return;
  bool f32 = flags[0] != 0;
  auto ld = [&](const void* p, int off) -> float {
    return f32 ? ((const float*)p)[off] : bf2f(((const u16*)p)[off]);
  };
  if (i >= 17216) {            // W2T[n][k], n<64, k<128  <- W2[k*64+n]
    int j = i - 17216, n = j >> 7, k = j & 127;
    w2t[j] = f2bf(ld(W2, k * 64 + n));
  } else if (i >= 832) {       // W1T[n][k], n<128, k<128 <- W1[k*128+n]
    int j = i - 832, n = j >> 7, k = j & 127;
    w1t[j] = f2bf(ld(W1, k * 128 + n));
  } else {
    const void* src; int off;
    if (i >= 768)      { src = b2;  off = i - 768; }
    else if (i >= 704) { src = a2d; off = i - 704; }
    else if (i >= 640) { src = a2s; off = i - 640; }
    else if (i >= 512) { src = bet; off = i - 512; }
    else if (i >= 384) { src = gam; off = i - 384; }
    else if (i >= 256) { src = b1;  off = i - 256; }
    else if (i >= 128) { src = a1d; off = i - 128; }
    else               { src = a1s; off = i; }
    smallf[i] = ld(src, off);
  }
}

// ---------------- CSR build (atomic-free two-level counting sort) ----------
__global__ __launch_bounds__(256) void k_hist(const int* __restrict__ ei,
                                              int* __restrict__ H,
                                              int* __restrict__ totals,
                                              const int* __restrict__ flags) {
  __shared__ int hist[NBK];
  int t = threadIdx.x, blk = blockIdx.x;
  for (int i = t; i < NBK; i += 256) hist[i] = 0;
  __syncthreads();
  bool i64 = flags[1] != 0;
  int base = blk * EPB;
  for (int k = 0; k < 32; k++) {
    int e = base + k * 256 + t;
    if (e < N_EDGES) {
      int d = i64 ? ei[2 * (N_EDGES + e)] : ei[N_EDGES + e];
      atomicAdd(&hist[d >> 8], 1);
    }
  }
  __syncthreads();
  for (int i = t; i < NBK; i += 256) {
    H[i * NBLK + blk] = hist[i];
    atomicAdd(&totals[i], hist[i]);
  }
}

__global__ void k_scan_tot(const int* __restrict__ totals, int* __restrict__ bucketBase) {
  __shared__ int tmp[256];
  int t = threadIdx.x;
  int v = (t < NBK) ? totals[t] : 0;
  tmp[t] = v; __syncthreads();
  for (int o = 1; o < 256; o <<= 1) {
    int x = (t >= o) ? tmp[t - o] : 0; __syncthreads();
    tmp[t] += x; __syncthreads();
  }
  if (t < NBK) bucketBase[t] = tmp[t] - v;
  if (t == NBK - 1) bucketBase[NBK] = tmp[t];
}

__global__ void k_scan_blk(const int* __restrict__ H, const int* __restrict__ bucketBase,
                           int* __restrict__ P) {
  __shared__ int tmp[256];
  int t = threadIdx.x, b = blockIdx.x;
  int v = (t < NBLK) ? H[b * NBLK + t] : 0;
  tmp[t] = v; __syncthreads();
  for (int o = 1; o < 256; o <<= 1) {
    int x = (t >= o) ? tmp[t - o] : 0; __syncthreads();
    tmp[t] += x; __syncthreads();
  }
  if (t < NBLK) P[b * NBLK + t] = bucketBase[b] + tmp[t] - v;
}

// k_bucket: LDS counting sort per 8192-edge tile, coalesced global writes.
__global__ __launch_bounds__(256) void k_bucket(const int* __restrict__ ei,
                                                const int* __restrict__ P,
                                                u32* __restrict__ buf,
                                                const int* __restrict__ flags) {
  __shared__ u32 sv[EPB];       // 32 KB sorted values
  __shared__ u16 rank[EPB];     // 16 KB rank within bucket
  __shared__ u8  sk8[EPB];      //  8 KB sorted keys
  __shared__ int cnt[NBK], scn[NBK], tmp[256];
  int t = threadIdx.x, blk = blockIdx.x;
  int base = blk * EPB;
  int nE = N_EDGES - base; if (nE > EPB) nE = EPB;
  for (int i = t; i < NBK; i += 256) cnt[i] = 0;
  __syncthreads();
  bool i64 = flags[1] != 0;
  // pass 1: rank capture
  for (int k = 0; k < EPB / 256; k++) {
    int li = k * 256 + t, e = base + li;
    if (li < nE) {
      int d = i64 ? ei[2 * (N_EDGES + e)] : ei[N_EDGES + e];
      rank[li] = (u16)atomicAdd(&cnt[d >> 8], 1);
    }
  }
  __syncthreads();
  // scan cnt -> scn (exclusive)
  int v = (t < NBK) ? cnt[t] : 0;
  tmp[t] = v; __syncthreads();
  for (int o = 1; o < 256; o <<= 1) {
    int x = (t >= o) ? tmp[t - o] : 0; __syncthreads();
    tmp[t] += x; __syncthreads();
  }
  if (t < NBK) scn[t] = tmp[t] - v;
  __syncthreads();
  // pass 2: place into LDS sorted order
  for (int k = 0; k < EPB / 256; k++) {
    int li = k * 256 + t, e = base + li;
    if (li < nE) {
      int s = i64 ? ei[2 * e] : ei[e];
      int d = i64 ? ei[2 * (N_EDGES + e)] : ei[N_EDGES + e];
      int key = d >> 8;
      int pos = scn[key] + rank[li];
      sv[pos] = ((u32)(d & 255) << 16) | (u32)s;
      sk8[pos] = (u8)key;
    }
  }
  __syncthreads();
  // pass 3: coalesced run writes
  for (int i = t; i < nE; i += 256) {
    int b = sk8[i];
    buf[P[b * NBLK + blk] + (i - scn[b])] = sv[i];
  }
}

__global__ __launch_bounds__(256) void k_csr(const u32* __restrict__ buf,
                                             const int* __restrict__ bucketBase,
                                             int* __restrict__ row_start,
                                             int* __restrict__ deg,
                                             int* __restrict__ csr, int N) {
  __shared__ int cnt[256], scn[256], cur[256];
  int b = blockIdx.x, t = threadIdx.x;
  int lo = bucketBase[b], hi = bucketBase[b + 1];
  cnt[t] = 0; __syncthreads();
  for (int e = lo + t; e < hi; e += 256) atomicAdd(&cnt[(buf[e] >> 16) & 255], 1);
  __syncthreads();
  int v = cnt[t];
  scn[t] = v; __syncthreads();
  for (int o = 1; o < 256; o <<= 1) {
    int x = (t >= o) ? scn[t - o] : 0; __syncthreads();
    scn[t] += x; __syncthreads();
  }
  int excl = scn[t] - v;
  int node = b * 256 + t;
  if (node < N) { row_start[node] = lo + excl; deg[node] = v; }
  cur[t] = lo + excl;
  __syncthreads();
  for (int e = lo + t; e < hi; e += 256) {
    u32 p = buf[e];
    int pos = atomicAdd(&cur[(p >> 16) & 255], 1);
    csr[pos] = p & 0xffff;
  }
}

// ---------------- MFMA GEMM: A[M,128] x BT[NCOLS,128] -> bf16 C[M,NCOLS] ----
// EPI fuses BN+ELU on A-load and alpha2 on the epilogue.
// A1 fuses per-head alpha1 (a1 dot products, 16-lane reductions) on epilogue.
// BLK writes C column-blocked [col>>5][row][col&31] for L2-resident gathers.
template <int NCOLS, bool EPI, bool AFLAG, bool A1, bool BLK>
__global__ __launch_bounds__(256) void k_gemm_mfma(const void* __restrict__ A,
                                                   const u16* __restrict__ BT,
                                                   const float* __restrict__ scale,
                                                   const float* __restrict__ shift,
                                                   const float* __restrict__ a2s,
                                                   const float* __restrict__ a2d,
                                                   float* __restrict__ as_out,
                                                   float* __restrict__ ad_out,
                                                   u16* __restrict__ C, int M,
                                                   const int* __restrict__ flags) {
  constexpr int KP = 136;
  constexpr int NT = NCOLS / 16;
  __shared__ u16 As[64 * KP];
  __shared__ u16 Bs[NCOLS * KP];
  int t = threadIdx.x;
  int row0 = blockIdx.x * 64;
  bool af32 = AFLAG ? (flags[0] != 0) : false;

  for (int i = t; i < NCOLS * 16; i += 256) {
    int n = i >> 4, q = i & 15;
    *(uint4*)&Bs[n * KP + q * 8] = ((const uint4*)BT)[n * 16 + q];
  }
  for (int i = t; i < 64 * 32; i += 256) {
    int r = i >> 5, c4 = i & 31;
    int row = row0 + r;
    uint2 pk = make_uint2(0u, 0u);
    if (row < M) {
      if (EPI) {
        uint2 p = ((const uint2*)A)[(size_t)row * 32 + c4];
        int c = c4 * 4;
        float v0 = bflo(p.x), v1 = bfhi(p.x), v2 = bflo(p.y), v3 = bfhi(p.y);
        v0 = fmaf(v0, scale[c],     shift[c]);     v0 = v0 > 0.f ? v0 : __expf(v0) - 1.f;
        v1 = fmaf(v1, scale[c + 1], shift[c + 1]); v1 = v1 > 0.f ? v1 : __expf(v1) - 1.f;
        v2 = fmaf(v2, scale[c + 2], shift[c + 2]); v2 = v2 > 0.f ? v2 : __expf(v2) - 1.f;
        v3 = fmaf(v3, scale[c + 3], shift[c + 3]); v3 = v3 > 0.f ? v3 : __expf(v3) - 1.f;
        pk.x = pack2(v0, v1); pk.y = pack2(v2, v3);
      } else if (af32) {
        float4 v = ((const float4*)A)[(size_t)row * 32 + c4];
        pk.x = pack2(v.x, v.y); pk.y = pack2(v.z, v.w);
      } else {
        pk = ((const uint2*)A)[(size_t)row * 32 + c4];
      }
    }
    *(uint2*)&As[r * KP + c4 * 4] = pk;
  }
  __syncthreads();

  int lane = t & 63, w = t >> 6;
  int m = lane & 15, quad = lane >> 4;
  f32x4 acc[NT];
#pragma unroll
  for (int nt = 0; nt < NT; nt++) acc[nt] = (f32x4)(0.f);
  const u16* aBase = &As[(w * 16 + m) * KP + quad * 8];
  const u16* bBase = &Bs[m * KP + quad * 8];
#pragma unroll
  for (int ks = 0; ks < 4; ks++) {
    bf16x8 af = *(const bf16x8*)(aBase + ks * 32);
#pragma unroll
    for (int nt = 0; nt < NT; nt++) {
      bf16x8 bf = *(const bf16x8*)(bBase + nt * 16 * KP + ks * 32);
      acc[nt] = __builtin_amdgcn_mfma_f32_16x16x32_bf16(af, bf, acc[nt], 0, 0, 0);
    }
  }
  int orow0 = row0 + w * 16 + quad * 4;
#pragma unroll
  for (int nt = 0; nt < NT; nt++) {
#pragma unroll
    for (int r = 0; r < 4; r++) {
      int row = orow0 + r;
      if (row < M) {
        if (BLK) {
          int col = nt * 16 + m;
          C[((size_t)(col >> 5) * N_NODES + row) * 32 + (col & 31)] = f2bf(acc[nt][r]);
        } else {
          C[(size_t)row * NCOLS + nt * 16 + m] = f2bf(acc[nt][r]);
        }
      }
    }
  }
  if (EPI) {  // fused alpha2: vs/vd per row, 16-lane reduction per quad group
    float a2sv[NT], a2dv[NT];
#pragma unroll
    for (int nt = 0; nt < NT; nt++) { a2sv[nt] = a2s[nt * 16 + m]; a2dv[nt] = a2d[nt * 16 + m]; }
#pragma unroll
    for (int r = 0; r < 4; r++) {
      float vs = 0.f, vd = 0.f;
#pragma unroll
      for (int nt = 0; nt < NT; nt++) {
        vs = fmaf(acc[nt][r], a2sv[nt], vs);
        vd = fmaf(acc[nt][r], a2dv[nt], vd);
      }
      vs += __shfl_xor(vs, 1); vd += __shfl_xor(vd, 1);
      vs += __shfl_xor(vs, 2); vd += __shfl_xor(vd, 2);
      vs += __shfl_xor(vs, 4); vd += __shfl_xor(vd, 4);
      vs += __shfl_xor(vs, 8); vd += __shfl_xor(vd, 8);
      int row = orow0 + r;
      if (row < M && m == 0) { as_out[row] = vs; ad_out[row] = vd; }
    }
  }
  if (A1) {  // fused alpha1: per-head (==nt) 16-lane reductions
    float s1v[NT], d1v[NT];
#pragma unroll
    for (int nt = 0; nt < NT; nt++) { s1v[nt] = a2s[nt * 16 + m]; d1v[nt] = a2d[nt * 16 + m]; }
#pragma unroll
    for (int r = 0; r < 4; r++) {
      int row = orow0 + r;
#pragma unroll
      for (int nt = 0; nt < NT; nt++) {
        float vs = acc[nt][r] * s1v[nt];
        float vd = acc[nt][r] * d1v[nt];
        vs += __shfl_xor(vs, 1); vd += __shfl_xor(vd, 1);
        vs += __shfl_xor(vs, 2); vd += __shfl_xor(vd, 2);
        vs += __shfl_xor(vs, 4); vd += __shfl_xor(vd, 4);
        vs += __shfl_xor(vs, 8); vd += __shfl_xor(vd, 8);
        if (row < M && m == 0) {
          as_out[(row << 3) | nt] = vs;
          ad_out[(row << 3) | nt] = vd;
        }
      }
    }
  }
}

// ---------------- aggregation layer 1: shared-exp unroll 8 (r1-verified) ----
__global__ __launch_bounds__(256) void k_agg1(const u16* __restrict__ h1b,
                                              const float* __restrict__ as_,
                                              const float* __restrict__ ad_,
                                              const int* __restrict__ csr,
                                              const int* __restrict__ row_start,
                                              const int* __restrict__ deg,
                                              const float* __restrict__ b1,
                                              u16* __restrict__ out, int N) {
  int node = blockIdx.x * 4 + (threadIdx.x >> 6);
  if (node >= N) return;
  int l = threadIdx.x & 63;
  int head = l >> 3, sub = l & 7;
  int gbase = l & 56;  // base lane of this head group
  int node_u = __builtin_amdgcn_readfirstlane(node);
  int st = __builtin_amdgcn_readfirstlane(row_start[node_u]);
  int cnt = __builtin_amdgcn_readfirstlane(deg[node_u]);
  const int* cp = csr + st;
  const u32* h32 = (const u32*)h1b;
  float ad = ad_[(node_u << 3) | head];
  float sp = 0.f, a0 = 0.f, a1 = 0.f;
  int j = 0;
  for (; j + 8 <= cnt; j += 8) {
    int ssub = cp[j + sub];                       // per-lane: my slot's src
    float e = as_[(ssub << 3) | head] + ad;
    e = fmaxf(e, 0.2f * e);
    float p = __expf(e);
    sp += p;                                      // per-lane partial of s
#pragma unroll
    for (int k = 0; k < 8; k++) {
      int sk = cp[j + k];                         // uniform -> s_load
      float pk = __shfl(p, gbase | k);
      u32 hv = h32[(sk << 6) | l];
      a0 = fmaf(pk, bflo(hv), a0);
      a1 = fmaf(pk, bfhi(hv), a1);
    }
  }
  for (; j < cnt; j++) {
    int s0 = cp[j];
    float e0 = as_[(s0 << 3) | head] + ad;
    e0 = fmaxf(e0, 0.2f * e0);
    float p0 = __expf(e0);
    if (sub == 0) sp += p0;
    u32 hv = h32[(s0 << 6) | l];
    a0 = fmaf(p0, bflo(hv), a0); a1 = fmaf(p0, bfhi(hv), a1);
  }
  { // self-loop
    float e0 = as_[(node_u << 3) | head] + ad;
    e0 = fmaxf(e0, 0.2f * e0);
    float p0 = __expf(e0);
    if (sub == 0) sp += p0;
    u32 hv = h32[((size_t)node_u << 6) | l];
    a0 = fmaf(p0, bflo(hv), a0); a1 = fmaf(p0, bfhi(hv), a1);
  }
  sp += __shfl_xor(sp, 1);
  sp += __shfl_xor(sp, 2);
  sp += __shfl_xor(sp, 4);
  float inv = 1.f / (sp + 1e-16f);
  int c0 = l * 2;
  ((u32*)out)[((size_t)node_u << 6) + l] =
      pack2(fmaf(a0, inv, b1[c0]), fmaf(a1, inv, b1[c0 + 1]));
}

// ---------------- batch norm ----------------
__global__ void k_bnstat(const u16* __restrict__ h, float* __restrict__ gsum,
                         float* __restrict__ gsq, int N) {
  __shared__ float ts[256], tq[256];
  int t = threadIdx.x, col = t & 127, rr = t >> 7;
  int row0 = blockIdx.x * 128;
  float s = 0.f, q = 0.f;
  for (int r = rr; r < 128; r += 2) {
    int row = row0 + r;
    if (row < N) {
      float v = bf2f(h[((size_t)row << 7) + col]);
      s += v; q = fmaf(v, v, q);
    }
  }
  ts[t] = s; tq[t] = q; __syncthreads();
  if (t < 128) {
    atomicAdd(&gsum[t], ts[t] + ts[t + 128]);
    atomicAdd(&gsq[t], tq[t] + tq[t + 128]);
  }
}

__global__ void k_bnfin(const float* __restrict__ gsum, const float* __restrict__ gsq,
                        const float* __restrict__ gamma, const float* __restrict__ beta,
                        float* __restrict__ scale, float* __restrict__ shift, int N) {
  int t = threadIdx.x;
  if (t >= 128) return;
  float mu = gsum[t] / (float)N;
  float var = fmaxf(gsq[t] / (float)N - mu * mu, 0.f);
  float s = gamma[t] * rsqrtf(var + 1e-5f);
  scale[t] = s;
  shift[t] = beta[t] - mu * s;
}

// ---------------- aggregation layer 2: 2-pass L2-resident column split ------
// Pass p covers u16 cols [32p,32p+32) of h2b stored blocked [2][N][32].
// Per-pass random working set = 3.2MB h-block + 0.2MB as_ < 4MiB L2/XCD;
// sequential launches ensure all XCDs converge on the same block.
// Wave = 1 node. Lane: eg=l>>4 (edge slot in gather), q=l&15 (u32 col).
// Exp lanes l<8 compute one edge's exp each; shfl-broadcast. VALU-neutral
// vs baseline: u32-paired fmas (2 cols/fma pair) offset the 2x exp/csr cost.
__global__ __launch_bounds__(256) void k_agg2p(const u16* __restrict__ h2b,
                                               const float* __restrict__ as_,
                                               const float* __restrict__ ad_,
                                               const int* __restrict__ csr,
                                               const int* __restrict__ row_start,
                                               const int* __restrict__ deg,
                                               const float* __restrict__ b2,
                                               void* __restrict__ out,
                                               const int* __restrict__ flags,
                                               int pass, int N) {
  int node = blockIdx.x * 4 + (threadIdx.x >> 6);
  if (node >= N) return;
  int l = threadIdx.x & 63;
  int eg = l >> 4;      // edge slot within gather group (0..3)
  int q  = l & 15;      // u32 col within the 16-u32 half-row
  int node_u = __builtin_amdgcn_readfirstlane(node);
  int st = __builtin_amdgcn_readfirstlane(row_start[node_u]);
  int cnt = __builtin_amdgcn_readfirstlane(deg[node_u]);
  const int* cp = csr + st;
  const u32* hp = (const u32*)h2b + (size_t)pass * (N_NODES * 16);
  float adv = ad_[node_u];
  float sp = 0.f, a0 = 0.f, a1 = 0.f;
  int nmain = cnt >> 3;
  for (int b = 0; b < nmain; b++) {
    int jb = b * 8;
    float p = 0.f;
    if (l < 8) {
      int s = cp[jb + l];
      float e = as_[s] + adv;
      e = fmaxf(e, 0.2f * e);
      p = __expf(e);
      sp += p;
    }
    int sA = cp[jb + eg];
    int sB = cp[jb + 4 + eg];
    u32 h0 = hp[(sA << 4) | q];
    u32 h1 = hp[(sB << 4) | q];
    float p0 = __shfl(p, eg);
    float p1 = __shfl(p, 4 + eg);
    a0 = fmaf(p0, bflo(h0), a0); a1 = fmaf(p0, bfhi(h0), a1);
    a0 = fmaf(p1, bflo(h1), a0); a1 = fmaf(p1, bfhi(h1), a1);
  }
  { // tail (cnt&7 edges) + self-loop in one masked 8-block; csr read-padded
    int jb = nmain * 8;
    int rem = cnt - jb;  // 0..7; slot rem = self-loop, slots > rem contribute 0
    float p = 0.f;
    if (l < 8) {
      int s = (l < rem) ? cp[jb + l] : node_u;
      float e = as_[s] + adv;
      e = fmaxf(e, 0.2f * e);
      p = (l <= rem) ? __expf(e) : 0.f;
      sp += p;
    }
    int sA = (eg < rem) ? cp[jb + eg] : node_u;
    int sB = (4 + eg < rem) ? cp[jb + 4 + eg] : node_u;
    u32 h0 = hp[(sA << 4) | q];
    u32 h1 = hp[(sB << 4) | q];
    float p0 = __shfl(p, eg);
    float p1 = __shfl(p, 4 + eg);
    a0 = fmaf(p0, bflo(h0), a0); a1 = fmaf(p0, bfhi(h0), a1);
    a0 = fmaf(p1, bflo(h1), a0); a1 = fmaf(p1, bfhi(h1), a1);
  }
  // reduce partial sums across the 4 edge-slot groups (bits 4,5 of lane)
  a0 += __shfl_xor(a0, 16); a0 += __shfl_xor(a0, 32);
  a1 += __shfl_xor(a1, 16); a1 += __shfl_xor(a1, 32);
  // softmax denominator: lanes 0..7 hold per-slot partials
  sp += __shfl_xor(sp, 1); sp += __shfl_xor(sp, 2); sp += __shfl_xor(sp, 4);
  float spx = __shfl(sp, 0);
  float inv = 1.f / (spx + 1e-16f);
  if (l < 16) {
    int c0 = (pass << 5) | (q << 1);
    float r0 = fmaf(a0, inv, b2[c0]);
    float r1 = fmaf(a1, inv, b2[c0 + 1]);
    if (flags[0]) {
      float2 rv = make_float2(r0, r1);
      *(float2*)&((float*)out)[((size_t)node_u << 6) | c0] = rv;
    } else {
      ((u32*)out)[((size_t)node_u << 5) | (pass << 4) | q] = pack2(r0, r1);
    }
  }
}

extern "C" void kernel_launch(void* const* d_in, const int* in_sizes, int n_in,
                              void* d_out, int out_size, void* d_ws, size_t ws_size,
                              hipStream_t stream) {
  const void* x   = d_in[0];
  const int*  ei  = (const int*)d_in[1];
  const void* W1  = d_in[2];
  const void* a1s = d_in[3];
  const void* a1d = d_in[4];
  const void* b1  = d_in[5];
  const void* gam = d_in[6];
  const void* bet = d_in[7];
  const void* W2  = d_in[8];
  const void* a2s = d_in[9];
  const void* a2d = d_in[10];
  const void* b2  = d_in[11];

  char* ws = (char*)d_ws;
  size_t off = 0;
  auto alloc = [&](size_t bytes) -> void* {
    void* p = ws + off;
    off += (bytes + 255) & ~(size_t)255;
    return p;
  };
  int* flags = (int*)alloc(256);
  char* zreg = (char*)alloc(2048);  // totals[196] | gsum[128] | gsq[128]
  int* totals = (int*)zreg;
  float* gsum = (float*)(zreg + 1024);
  float* gsq  = gsum + 128;
  int* H  = (int*)alloc((size_t)NBK * NBLK * 4);
  int* P  = (int*)alloc((size_t)NBK * NBLK * 4);
  int* bucketBase = (int*)alloc(1024);
  u32* ebuf = (u32*)alloc((size_t)N_EDGES * 4);
  int* csr = (int*)alloc(((size_t)N_EDGES + 64) * 4);
  int* row_start = (int*)alloc((size_t)N_NODES * 4);
  int* deg = (int*)alloc((size_t)N_NODES * 4);
  float* smallf = (float*)alloc(832 * 4);
  float* a1sf = smallf;        float* a1df = smallf + 128;
  float* b1f  = smallf + 256;  float* gamf = smallf + 384;
  float* betf = smallf + 512;  float* a2sf = smallf + 640;
  float* a2df = smallf + 704;  float* b2f  = smallf + 768;
  u16* w1t = (u16*)alloc(16384 * 2);
  u16* w2t = (u16*)alloc(8192 * 2);
  u16* h1b  = (u16*)alloc((size_t)N_NODES * 128 * 2);
  u16* h1ob = (u16*)alloc((size_t)N_NODES * 128 * 2);
  u16* h2b  = (u16*)alloc((size_t)N_NODES * 64 * 2);   // column-blocked [2][N][32]
  float* al1s = (float*)alloc((size_t)N_NODES * 8 * 4);
  float* al1d = (float*)alloc((size_t)N_NODES * 8 * 4);
  float* scale = (float*)alloc(512);
  float* shift = (float*)alloc(512);
  float* al2s = (float*)alloc((size_t)N_NODES * 4);
  float* al2d = (float*)alloc((size_t)N_NODES * 4);
  if (off > ws_size) return;

  hipMemsetAsync(zreg, 0, 2048, stream);
  k_detect<<<1, 256, 0, stream>>>((const u16*)x, (const u32*)ei, flags);
  k_convsmall<<<100, 256, 0, stream>>>(a1s, a1d, b1, gam, bet, a2s, a2d, b2, W1, W2,
                                       smallf, w1t, w2t, flags);

  // ---- CSR build (r1 measured-good 196-bucket counting sort) ----
  k_hist<<<NBLK, 256, 0, stream>>>(ei, H, totals, flags);
  k_scan_tot<<<1, 256, 0, stream>>>(totals, bucketBase);
  k_scan_blk<<<NBK, 256, 0, stream>>>(H, bucketBase, P);
  k_bucket<<<NBLK, 256, 0, stream>>>(ei, P, ebuf, flags);
  k_csr<<<NBK, 256, 0, stream>>>(ebuf, bucketBase, row_start, deg, csr, N_NODES);

  // ---- layer 1 (alpha1 fused into GEMM epilogue) ----
  k_gemm_mfma<128, false, true, true, false><<<(N_NODES + 63) / 64, 256, 0, stream>>>(
      x, w1t, nullptr, nullptr, a1sf, a1df, al1s, al1d, h1b, N_NODES, flags);
  k_agg1<<<(N_NODES + 3) / 4, 256, 0, stream>>>(h1b, al1s, al1d, csr, row_start, deg,
                                                b1f, h1ob, N_NODES);

  // ---- BN ----
  k_bnstat<<<(N_NODES + 127) / 128, 256, 0, stream>>>(h1ob, gsum, gsq, N_NODES);
  k_bnfin<<<1, 128, 0, stream>>>(gsum, gsq, gamf, betf, scale, shift, N_NODES);

  // ---- layer 2 (alpha2 fused into GEMM epilogue; h2b column-blocked) ----
  k_gemm_mfma<64, true, false, false, true><<<(N_NODES + 63) / 64, 256, 0, stream>>>(
      h1ob, w2t, scale, shift, a2sf, a2df, al2s, al2d, h2b, N_NODES, flags);
  k_agg2p<<<(N_NODES + 3) / 4, 256, 0, stream>>>(h2b, al2s, al2d, csr, row_start, deg,
                                                 b2f, d_out, flags, 0, N_NODES);
  k_agg2p<<<(N_NODES + 3) / 4, 256, 0, stream>>>(h2b, al2s, al2d, csr, row_start, deg,
                                                 b2f, d_out, flags, 1, N_NODES);
}

// Round 8
// 327.824 us; speedup vs baseline: 1.1681x; 1.1681x over previous
//
#include <hip/hip_runtime.h>
#include <hip/hip_bf16.h>

#define N_NODES 50000
#define N_EDGES 1600000
#define HEADS 8
#define NBK 196   // buckets: dst>>8
#define NBLK 196  // edge tiles: 196*8192 >= 1.6M
#define EPB 8192  // edges per bucket-build block

typedef unsigned short u16;
typedef unsigned char u8;
typedef unsigned int u32;
typedef __attribute__((ext_vector_type(8))) short bf16x8;
typedef __attribute__((ext_vector_type(4))) float f32x4;

__device__ __forceinline__ float bf2f(u16 u) {
  union { u32 i; float f; } v; v.i = ((u32)u) << 16; return v.f;
}
__device__ __forceinline__ float bflo(u32 p) {
  union { u32 i; float f; } v; v.i = p << 16; return v.f;
}
__device__ __forceinline__ float bfhi(u32 p) {
  union { u32 i; float f; } v; v.i = p & 0xffff0000u; return v.f;
}
__device__ __forceinline__ u16 f2bf(float f) {
  union { float f; u32 i; } v; v.f = f;
  u32 r = v.i + 0x7fff + ((v.i >> 16) & 1);  // RNE
  return (u16)(r >> 16);
}
__device__ __forceinline__ u32 pack2(float a, float b) {
  return (u32)f2bf(a) | ((u32)f2bf(b) << 16);
}

// ---------------- dtype auto-detection ----------------
__global__ void k_detect(const u16* __restrict__ x, const u32* __restrict__ ei,
                         int* __restrict__ flags) {
  __shared__ int cbig, cnz;
  if (threadIdx.x == 0) { cbig = 0; cnz = 0; }
  __syncthreads();
  int lb = 0, ln = 0;
  for (int i = threadIdx.x; i < 4096; i += 256) {
    int ex = (x[i] >> 7) & 0xff;
    lb += (ex >= 140);
    if (i < 2048) ln += (ei[2 * i + 1] != 0);
  }
  atomicAdd(&cbig, lb); atomicAdd(&cnz, ln);
  __syncthreads();
  if (threadIdx.x == 0) {
    flags[0] = (cbig > 16) ? 1 : 0;   // 1: floats are fp32
    flags[1] = (cnz == 0) ? 1 : 0;    // 1: edge_index is int64
  }
}

// ---------------- converter: vectors -> fp32, W1/W2 -> transposed bf16 -------
__global__ void k_convsmall(const void* a1s, const void* a1d, const void* b1,
                            const void* gam, const void* bet, const void* a2s,
                            const void* a2d, const void* b2, const void* W1,
                            const void* W2, float* __restrict__ smallf,
                            u16* __restrict__ w1t, u16* __restrict__ w2t,
                            const int* __restrict__ flags) {
  int i = blockIdx.x * 256 + threadIdx.x;
  if (i >= 25408) return;
  bool f32 = flags[0] != 0;
  auto ld = [&](const void* p, int off) -> float {
    return f32 ? ((const float*)p)[off] : bf2f(((const u16*)p)[off]);
  };
  if (i >= 17216) {            // W2T[n][k], n<64, k<128  <- W2[k*64+n]
    int j = i - 17216, n = j >> 7, k = j & 127;
    w2t[j] = f2bf(ld(W2, k * 64 + n));
  } else if (i >= 832) {       // W1T[n][k], n<128, k<128 <- W1[k*128+n]
    int j = i - 832, n = j >> 7, k = j & 127;
    w1t[j] = f2bf(ld(W1, k * 128 + n));
  } else {
    const void* src; int off;
    if (i >= 768)      { src = b2;  off = i - 768; }
    else if (i >= 704) { src = a2d; off = i - 704; }
    else if (i >= 640) { src = a2s; off = i - 640; }
    else if (i >= 512) { src = bet; off = i - 512; }
    else if (i >= 384) { src = gam; off = i - 384; }
    else if (i >= 256) { src = b1;  off = i - 256; }
    else if (i >= 128) { src = a1d; off = i - 128; }
    else               { src = a1s; off = i; }
    smallf[i] = ld(src, off);
  }
}

// ---------------- CSR build (atomic-free two-level counting sort) ----------
__global__ __launch_bounds__(256) void k_hist(const int* __restrict__ ei,
                                              int* __restrict__ H,
                                              int* __restrict__ totals,
                                              const int* __restrict__ flags) {
  __shared__ int hist[NBK];
  int t = threadIdx.x, blk = blockIdx.x;
  for (int i = t; i < NBK; i += 256) hist[i] = 0;
  __syncthreads();
  bool i64 = flags[1] != 0;
  int base = blk * EPB;
  for (int k = 0; k < 32; k++) {
    int e = base + k * 256 + t;
    if (e < N_EDGES) {
      int d = i64 ? ei[2 * (N_EDGES + e)] : ei[N_EDGES + e];
      atomicAdd(&hist[d >> 8], 1);
    }
  }
  __syncthreads();
  for (int i = t; i < NBK; i += 256) {
    H[i * NBLK + blk] = hist[i];
    atomicAdd(&totals[i], hist[i]);
  }
}

__global__ void k_scan_tot(const int* __restrict__ totals, int* __restrict__ bucketBase) {
  __shared__ int tmp[256];
  int t = threadIdx.x;
  int v = (t < NBK) ? totals[t] : 0;
  tmp[t] = v; __syncthreads();
  for (int o = 1; o < 256; o <<= 1) {
    int x = (t >= o) ? tmp[t - o] : 0; __syncthreads();
    tmp[t] += x; __syncthreads();
  }
  if (t < NBK) bucketBase[t] = tmp[t] - v;
  if (t == NBK - 1) bucketBase[NBK] = tmp[t];
}

__global__ void k_scan_blk(const int* __restrict__ H, const int* __restrict__ bucketBase,
                           int* __restrict__ P) {
  __shared__ int tmp[256];
  int t = threadIdx.x, b = blockIdx.x;
  int v = (t < NBLK) ? H[b * NBLK + t] : 0;
  tmp[t] = v; __syncthreads();
  for (int o = 1; o < 256; o <<= 1) {
    int x = (t >= o) ? tmp[t - o] : 0; __syncthreads();
    tmp[t] += x; __syncthreads();
  }
  if (t < NBLK) P[b * NBLK + t] = bucketBase[b] + tmp[t] - v;
}

// k_bucket v2: LDS counting sort per 8192-edge tile, coalesced global writes.
__global__ __launch_bounds__(256) void k_bucket(const int* __restrict__ ei,
                                                const int* __restrict__ P,
                                                u32* __restrict__ buf,
                                                const int* __restrict__ flags) {
  __shared__ u32 sv[EPB];       // 32 KB sorted values
  __shared__ u16 rank[EPB];     // 16 KB rank within bucket
  __shared__ u8  sk8[EPB];      //  8 KB sorted keys
  __shared__ int cnt[NBK], scn[NBK], tmp[256];
  int t = threadIdx.x, blk = blockIdx.x;
  int base = blk * EPB;
  int nE = N_EDGES - base; if (nE > EPB) nE = EPB;
  for (int i = t; i < NBK; i += 256) cnt[i] = 0;
  __syncthreads();
  bool i64 = flags[1] != 0;
  // pass 1: rank capture
  for (int k = 0; k < EPB / 256; k++) {
    int li = k * 256 + t, e = base + li;
    if (li < nE) {
      int d = i64 ? ei[2 * (N_EDGES + e)] : ei[N_EDGES + e];
      rank[li] = (u16)atomicAdd(&cnt[d >> 8], 1);
    }
  }
  __syncthreads();
  // scan cnt -> scn (exclusive)
  int v = (t < NBK) ? cnt[t] : 0;
  tmp[t] = v; __syncthreads();
  for (int o = 1; o < 256; o <<= 1) {
    int x = (t >= o) ? tmp[t - o] : 0; __syncthreads();
    tmp[t] += x; __syncthreads();
  }
  if (t < NBK) scn[t] = tmp[t] - v;
  __syncthreads();
  // pass 2: place into LDS sorted order
  for (int k = 0; k < EPB / 256; k++) {
    int li = k * 256 + t, e = base + li;
    if (li < nE) {
      int s = i64 ? ei[2 * e] : ei[e];
      int d = i64 ? ei[2 * (N_EDGES + e)] : ei[N_EDGES + e];
      int key = d >> 8;
      int pos = scn[key] + rank[li];
      sv[pos] = ((u32)(d & 255) << 16) | (u32)s;
      sk8[pos] = (u8)key;
    }
  }
  __syncthreads();
  // pass 3: coalesced run writes
  for (int i = t; i < nE; i += 256) {
    int b = sk8[i];
    buf[P[b * NBLK + blk] + (i - scn[b])] = sv[i];
  }
}

__global__ __launch_bounds__(256) void k_csr(const u32* __restrict__ buf,
                                             const int* __restrict__ bucketBase,
                                             int* __restrict__ row_start,
                                             int* __restrict__ deg,
                                             int* __restrict__ csr, int N) {
  __shared__ int cnt[256], scn[256], cur[256];
  int b = blockIdx.x, t = threadIdx.x;
  int lo = bucketBase[b], hi = bucketBase[b + 1];
  cnt[t] = 0; __syncthreads();
  for (int e = lo + t; e < hi; e += 256) atomicAdd(&cnt[(buf[e] >> 16) & 255], 1);
  __syncthreads();
  int v = cnt[t];
  scn[t] = v; __syncthreads();
  for (int o = 1; o < 256; o <<= 1) {
    int x = (t >= o) ? scn[t - o] : 0; __syncthreads();
    scn[t] += x; __syncthreads();
  }
  int excl = scn[t] - v;
  int node = b * 256 + t;
  if (node < N) { row_start[node] = lo + excl; deg[node] = v; }
  cur[t] = lo + excl;
  __syncthreads();
  for (int e = lo + t; e < hi; e += 256) {
    u32 p = buf[e];
    int pos = atomicAdd(&cur[(p >> 16) & 255], 1);
    csr[pos] = p & 0xffff;
  }
}

// ---------------- MFMA GEMM: A[M,128] x BT[NCOLS,128] -> bf16 C[M,NCOLS] ----
// EPI also fuses BN+ELU on A-load and alpha2 (a2 dot products) on the epilogue.
template <int NCOLS, bool EPI, bool AFLAG>
__global__ __launch_bounds__(256) void k_gemm_mfma(const void* __restrict__ A,
                                                   const u16* __restrict__ BT,
                                                   const float* __restrict__ scale,
                                                   const float* __restrict__ shift,
                                                   const float* __restrict__ a2s,
                                                   const float* __restrict__ a2d,
                                                   float* __restrict__ as_out,
                                                   float* __restrict__ ad_out,
                                                   u16* __restrict__ C, int M,
                                                   const int* __restrict__ flags) {
  constexpr int KP = 136;
  constexpr int NT = NCOLS / 16;
  __shared__ u16 As[64 * KP];
  __shared__ u16 Bs[NCOLS * KP];
  int t = threadIdx.x;
  int row0 = blockIdx.x * 64;
  bool af32 = AFLAG ? (flags[0] != 0) : false;

  for (int i = t; i < NCOLS * 16; i += 256) {
    int n = i >> 4, q = i & 15;
    *(uint4*)&Bs[n * KP + q * 8] = ((const uint4*)BT)[n * 16 + q];
  }
  for (int i = t; i < 64 * 32; i += 256) {
    int r = i >> 5, c4 = i & 31;
    int row = row0 + r;
    uint2 pk = make_uint2(0u, 0u);
    if (row < M) {
      if (EPI) {
        uint2 p = ((const uint2*)A)[(size_t)row * 32 + c4];
        int c = c4 * 4;
        float v0 = bflo(p.x), v1 = bfhi(p.x), v2 = bflo(p.y), v3 = bfhi(p.y);
        v0 = fmaf(v0, scale[c],     shift[c]);     v0 = v0 > 0.f ? v0 : __expf(v0) - 1.f;
        v1 = fmaf(v1, scale[c + 1], shift[c + 1]); v1 = v1 > 0.f ? v1 : __expf(v1) - 1.f;
        v2 = fmaf(v2, scale[c + 2], shift[c + 2]); v2 = v2 > 0.f ? v2 : __expf(v2) - 1.f;
        v3 = fmaf(v3, scale[c + 3], shift[c + 3]); v3 = v3 > 0.f ? v3 : __expf(v3) - 1.f;
        pk.x = pack2(v0, v1); pk.y = pack2(v2, v3);
      } else if (af32) {
        float4 v = ((const float4*)A)[(size_t)row * 32 + c4];
        pk.x = pack2(v.x, v.y); pk.y = pack2(v.z, v.w);
      } else {
        pk = ((const uint2*)A)[(size_t)row * 32 + c4];
      }
    }
    *(uint2*)&As[r * KP + c4 * 4] = pk;
  }
  __syncthreads();

  int lane = t & 63, w = t >> 6;
  int m = lane & 15, quad = lane >> 4;
  f32x4 acc[NT];
#pragma unroll
  for (int nt = 0; nt < NT; nt++) acc[nt] = (f32x4)(0.f);
  const u16* aBase = &As[(w * 16 + m) * KP + quad * 8];
  const u16* bBase = &Bs[m * KP + quad * 8];
#pragma unroll
  for (int ks = 0; ks < 4; ks++) {
    bf16x8 af = *(const bf16x8*)(aBase + ks * 32);
#pragma unroll
    for (int nt = 0; nt < NT; nt++) {
      bf16x8 bf = *(const bf16x8*)(bBase + nt * 16 * KP + ks * 32);
      acc[nt] = __builtin_amdgcn_mfma_f32_16x16x32_bf16(af, bf, acc[nt], 0, 0, 0);
    }
  }
  int orow0 = row0 + w * 16 + quad * 4;
#pragma unroll
  for (int nt = 0; nt < NT; nt++) {
#pragma unroll
    for (int r = 0; r < 4; r++) {
      int row = orow0 + r;
      if (row < M) C[(size_t)row * NCOLS + nt * 16 + m] = f2bf(acc[nt][r]);
    }
  }
  if (EPI) {  // fused alpha2: vs/vd per row, 16-lane reduction per quad group
    float a2sv[NT], a2dv[NT];
#pragma unroll
    for (int nt = 0; nt < NT; nt++) { a2sv[nt] = a2s[nt * 16 + m]; a2dv[nt] = a2d[nt * 16 + m]; }
#pragma unroll
    for (int r = 0; r < 4; r++) {
      float vs = 0.f, vd = 0.f;
#pragma unroll
      for (int nt = 0; nt < NT; nt++) {
        vs = fmaf(acc[nt][r], a2sv[nt], vs);
        vd = fmaf(acc[nt][r], a2dv[nt], vd);
      }
      vs += __shfl_xor(vs, 1); vd += __shfl_xor(vd, 1);
      vs += __shfl_xor(vs, 2); vd += __shfl_xor(vd, 2);
      vs += __shfl_xor(vs, 4); vd += __shfl_xor(vd, 4);
      vs += __shfl_xor(vs, 8); vd += __shfl_xor(vd, 8);
      int row = orow0 + r;
      if (row < M && m == 0) { as_out[row] = vs; ad_out[row] = vd; }
    }
  }
}

// ---------------- per-node attention coefficients, layer 1 ----------------
__global__ void k_alpha1(const u16* __restrict__ h1b, const float* __restrict__ a1s,
                         const float* __restrict__ a1d, float* __restrict__ as_out,
                         float* __restrict__ ad_out, int N) {
  int idx = blockIdx.x * 256 + threadIdx.x;
  if (idx >= N * HEADS) return;
  int n = idx >> 3, h = idx & 7;
  const u32* hp = (const u32*)&h1b[((size_t)n << 7) + (h << 4)];
  float s = 0.f, d = 0.f;
#pragma unroll
  for (int q = 0; q < 8; q++) {
    u32 p = hp[q];
    float v0 = bflo(p), v1 = bfhi(p);
    int b = (h << 4) + q * 2;
    s = fmaf(v0, a1s[b], s); s = fmaf(v1, a1s[b + 1], s);
    d = fmaf(v0, a1d[b], d); d = fmaf(v1, a1d[b + 1], d);
  }
  as_out[idx] = s; ad_out[idx] = d;
}

// ---------------- aggregation layer 1: shared-exp unroll 8 ----------------
// lane (head=l>>3, sub=l&7) computes exp for (edge=sub, head); p distributed
// to the other 7 lanes of the head group via shfl; s via group reduction.
__global__ __launch_bounds__(256) void k_agg1(const u16* __restrict__ h1b,
                                              const float* __restrict__ as_,
                                              const float* __restrict__ ad_,
                                              const int* __restrict__ csr,
                                              const int* __restrict__ row_start,
                                              const int* __restrict__ deg,
                                              const float* __restrict__ b1,
                                              u16* __restrict__ out, int N) {
  int node = blockIdx.x * 4 + (threadIdx.x >> 6);
  if (node >= N) return;
  int l = threadIdx.x & 63;
  int head = l >> 3, sub = l & 7;
  int gbase = l & 56;  // base lane of this head group
  int node_u = __builtin_amdgcn_readfirstlane(node);
  int st = __builtin_amdgcn_readfirstlane(row_start[node_u]);
  int cnt = __builtin_amdgcn_readfirstlane(deg[node_u]);
  const int* cp = csr + st;
  const u32* h32 = (const u32*)h1b;
  float ad = ad_[(node_u << 3) | head];
  float sp = 0.f, a0 = 0.f, a1 = 0.f;
  int j = 0;
  for (; j + 8 <= cnt; j += 8) {
    int ssub = cp[j + sub];                       // per-lane: my slot's src
    float e = as_[(ssub << 3) | head] + ad;
    e = fmaxf(e, 0.2f * e);
    float p = __expf(e);
    sp += p;                                      // per-lane partial of s
#pragma unroll
    for (int k = 0; k < 8; k++) {
      int sk = cp[j + k];                         // uniform -> s_load
      float pk = __shfl(p, gbase | k);
      u32 hv = h32[(sk << 6) | l];
      a0 = fmaf(pk, bflo(hv), a0);
      a1 = fmaf(pk, bfhi(hv), a1);
    }
  }
  for (; j < cnt; j++) {
    int s0 = cp[j];
    float e0 = as_[(s0 << 3) | head] + ad;
    e0 = fmaxf(e0, 0.2f * e0);
    float p0 = __expf(e0);
    if (sub == 0) sp += p0;
    u32 hv = h32[(s0 << 6) | l];
    a0 = fmaf(p0, bflo(hv), a0); a1 = fmaf(p0, bfhi(hv), a1);
  }
  { // self-loop
    float e0 = as_[(node_u << 3) | head] + ad;
    e0 = fmaxf(e0, 0.2f * e0);
    float p0 = __expf(e0);
    if (sub == 0) sp += p0;
    u32 hv = h32[((size_t)node_u << 6) | l];
    a0 = fmaf(p0, bflo(hv), a0); a1 = fmaf(p0, bfhi(hv), a1);
  }
  sp += __shfl_xor(sp, 1);
  sp += __shfl_xor(sp, 2);
  sp += __shfl_xor(sp, 4);
  float inv = 1.f / (sp + 1e-16f);
  int c0 = l * 2;
  ((u32*)out)[((size_t)node_u << 6) + l] =
      pack2(fmaf(a0, inv, b1[c0]), fmaf(a1, inv, b1[c0 + 1]));
}

// ---------------- batch norm ----------------
__global__ void k_bnstat(const u16* __restrict__ h, float* __restrict__ gsum,
                         float* __restrict__ gsq, int N) {
  __shared__ float ts[256], tq[256];
  int t = threadIdx.x, col = t & 127, rr = t >> 7;
  int row0 = blockIdx.x * 128;
  float s = 0.f, q = 0.f;
  for (int r = rr; r < 128; r += 2) {
    int row = row0 + r;
    if (row < N) {
      float v = bf2f(h[((size_t)row << 7) + col]);
      s += v; q = fmaf(v, v, q);
    }
  }
  ts[t] = s; tq[t] = q; __syncthreads();
  if (t < 128) {
    atomicAdd(&gsum[t], ts[t] + ts[t + 128]);
    atomicAdd(&gsq[t], tq[t] + tq[t + 128]);
  }
}

__global__ void k_bnfin(const float* __restrict__ gsum, const float* __restrict__ gsq,
                        const float* __restrict__ gamma, const float* __restrict__ beta,
                        float* __restrict__ scale, float* __restrict__ shift, int N) {
  int t = threadIdx.x;
  if (t >= 128) return;
  float mu = gsum[t] / (float)N;
  float var = fmaxf(gsq[t] / (float)N - mu * mu, 0.f);
  float s = gamma[t] * rsqrtf(var + 1e-5f);
  scale[t] = s;
  shift[t] = beta[t] - mu * s;
}

// ---------------- aggregation layer 2 -> output (shared-exp unroll 8) -------
__global__ __launch_bounds__(256) void k_agg2(const u16* __restrict__ h2b,
                                              const float* __restrict__ as_,
                                              const float* __restrict__ ad_,
                                              const int* __restrict__ csr,
                                              const int* __restrict__ row_start,
                                              const int* __restrict__ deg,
                                              const float* __restrict__ b2,
                                              void* __restrict__ out,
                                              const int* __restrict__ flags, int N) {
  int node = blockIdx.x * 4 + (threadIdx.x >> 6);
  if (node >= N) return;
  int l = threadIdx.x & 63;
  int sub = l & 7, gbase = l & 56;
  int node_u = __builtin_amdgcn_readfirstlane(node);
  int st = __builtin_amdgcn_readfirstlane(row_start[node_u]);
  int cnt = __builtin_amdgcn_readfirstlane(deg[node_u]);
  const int* cp = csr + st;
  float ad = ad_[node_u];
  float sp = 0.f, a = 0.f;
  int j = 0;
  for (; j + 8 <= cnt; j += 8) {
    int ssub = cp[j + sub];
    float e = as_[ssub] + ad;
    e = fmaxf(e, 0.2f * e);
    float p = __expf(e);
    sp += p;
#pragma unroll
    for (int k = 0; k < 8; k++) {
      int sk = cp[j + k];                         // uniform -> s_load
      float pk = __shfl(p, gbase | k);
      a = fmaf(pk, bf2f((h2b + (sk << 6))[l]), a);
    }
  }
  for (; j < cnt; j++) {
    int s0 = cp[j];
    float e0 = as_[s0] + ad;
    e0 = fmaxf(e0, 0.2f * e0);
    float p0 = __expf(e0);
    if (sub == 0) sp += p0;
    a = fmaf(p0, bf2f((h2b + (s0 << 6))[l]), a);
  }
  { // self-loop
    float e0 = as_[node_u] + ad;
    e0 = fmaxf(e0, 0.2f * e0);
    float p0 = __expf(e0);
    if (sub == 0) sp += p0;
    a = fmaf(p0, bf2f((h2b + (node_u << 6))[l]), a);
  }
  sp += __shfl_xor(sp, 1);
  sp += __shfl_xor(sp, 2);
  sp += __shfl_xor(sp, 4);
  float r = a / (sp + 1e-16f) + b2[l];
  size_t idx = ((size_t)node_u << 6) + l;
  if (flags[0]) ((float*)out)[idx] = r;
  else          ((u16*)out)[idx] = f2bf(r);
}

extern "C" void kernel_launch(void* const* d_in, const int* in_sizes, int n_in,
                              void* d_out, int out_size, void* d_ws, size_t ws_size,
                              hipStream_t stream) {
  const void* x   = d_in[0];
  const int*  ei  = (const int*)d_in[1];
  const void* W1  = d_in[2];
  const void* a1s = d_in[3];
  const void* a1d = d_in[4];
  const void* b1  = d_in[5];
  const void* gam = d_in[6];
  const void* bet = d_in[7];
  const void* W2  = d_in[8];
  const void* a2s = d_in[9];
  const void* a2d = d_in[10];
  const void* b2  = d_in[11];

  char* ws = (char*)d_ws;
  size_t off = 0;
  auto alloc = [&](size_t bytes) -> void* {
    void* p = ws + off;
    off += (bytes + 255) & ~(size_t)255;
    return p;
  };
  int* flags = (int*)alloc(256);
  char* zreg = (char*)alloc(2048);  // totals[196] | gsum[128] | gsq[128]
  int* totals = (int*)zreg;
  float* gsum = (float*)(zreg + 1024);
  float* gsq  = gsum + 128;
  int* H  = (int*)alloc((size_t)NBK * NBLK * 4);
  int* P  = (int*)alloc((size_t)NBK * NBLK * 4);
  int* bucketBase = (int*)alloc(1024);
  u32* ebuf = (u32*)alloc((size_t)N_EDGES * 4);
  int* csr = (int*)alloc((size_t)N_EDGES * 4);
  int* row_start = (int*)alloc((size_t)N_NODES * 4);
  int* deg = (int*)alloc((size_t)N_NODES * 4);
  float* smallf = (float*)alloc(832 * 4);
  float* a1sf = smallf;        float* a1df = smallf + 128;
  float* b1f  = smallf + 256;  float* gamf = smallf + 384;
  float* betf = smallf + 512;  float* a2sf = smallf + 640;
  float* a2df = smallf + 704;  float* b2f  = smallf + 768;
  u16* w1t = (u16*)alloc(16384 * 2);
  u16* w2t = (u16*)alloc(8192 * 2);
  u16* h1b  = (u16*)alloc((size_t)N_NODES * 128 * 2);
  u16* h1ob = (u16*)alloc((size_t)N_NODES * 128 * 2);
  u16* h2b  = (u16*)alloc((size_t)N_NODES * 64 * 2);
  float* al1s = (float*)alloc((size_t)N_NODES * 8 * 4);
  float* al1d = (float*)alloc((size_t)N_NODES * 8 * 4);
  float* scale = (float*)alloc(512);
  float* shift = (float*)alloc(512);
  float* al2s = (float*)alloc((size_t)N_NODES * 4);
  float* al2d = (float*)alloc((size_t)N_NODES * 4);
  if (off > ws_size) return;

  hipMemsetAsync(zreg, 0, 2048, stream);
  k_detect<<<1, 256, 0, stream>>>((const u16*)x, (const u32*)ei, flags);
  k_convsmall<<<100, 256, 0, stream>>>(a1s, a1d, b1, gam, bet, a2s, a2d, b2, W1, W2,
                                       smallf, w1t, w2t, flags);

  // ---- CSR build ----
  k_hist<<<NBLK, 256, 0, stream>>>(ei, H, totals, flags);
  k_scan_tot<<<1, 256, 0, stream>>>(totals, bucketBase);
  k_scan_blk<<<NBK, 256, 0, stream>>>(H, bucketBase, P);
  k_bucket<<<NBLK, 256, 0, stream>>>(ei, P, ebuf, flags);
  k_csr<<<NBK, 256, 0, stream>>>(ebuf, bucketBase, row_start, deg, csr, N_NODES);

  // ---- layer 1 ----
  k_gemm_mfma<128, false, true><<<(N_NODES + 63) / 64, 256, 0, stream>>>(
      x, w1t, nullptr, nullptr, nullptr, nullptr, nullptr, nullptr, h1b, N_NODES, flags);
  k_alpha1<<<(N_NODES * HEADS + 255) / 256, 256, 0, stream>>>(h1b, a1sf, a1df,
                                                              al1s, al1d, N_NODES);
  k_agg1<<<(N_NODES + 3) / 4, 256, 0, stream>>>(h1b, al1s, al1d, csr, row_start, deg,
                                                b1f, h1ob, N_NODES);

  // ---- BN ----
  k_bnstat<<<(N_NODES + 127) / 128, 256, 0, stream>>>(h1ob, gsum, gsq, N_NODES);
  k_bnfin<<<1, 128, 0, stream>>>(gsum, gsq, gamf, betf, scale, shift, N_NODES);

  // ---- layer 2 (alpha2 fused into GEMM epilogue) ----
  k_gemm_mfma<64, true, false><<<(N_NODES + 63) / 64, 256, 0, stream>>>(
      h1ob, w2t, scale, shift, a2sf, a2df, al2s, al2d, h2b, N_NODES, flags);
  k_agg2<<<(N_NODES + 3) / 4, 256, 0, stream>>>(h2b, al2s, al2d, csr, row_start, deg,
                                                b2f, d_out, flags, N_NODES);
}